// Round 5
// baseline (223.187 us; speedup 1.0000x reference)
//
#include <hip/hip_runtime.h>

// HungarianCELoss — analytic collapse of the 120-perm matching.
// targets has only 2 distinct rows (fg, bg=1-fg) => argmin over perms ==
// argmin_k (cost_fg[k]-cost_bg[k]), ties -> smallest k (lex order of perms).
// Per-element identities (x = slot logit, fg = target):
//   e = exp(-|x|); softplus(x)-x = log(1+e) + max(-x,0) = d; sigmoid = exp(-d)
//   sigmoid(x) = (x>=0) ? 1/(1+e) : e/(1+e)   (rcp path, shorter dep chain)
//   sum_k A_k = sum d (all k,n) + sum_k XF_k,  C_k = 2*XF_k - X_k
//   answer = [sum_k A_k - C_{k*}] summed over b, / (B*K*N)
//
// R5: pass1 is latency-bound (R1: FETCH 78MB but 95us; VALUBusy 27%), not
// BW-bound. Rotating depth-4 prefetch keeps 8 loads/wave in flight with a
// one-outer-body use distance; slot loads are non-temporal (zero reuse).

#define BB 64
#define KK 5
#define NPIX 102400     // 320*320
#define NSEG 5
#define SEG 20480       // NPIX / NSEG  (80 KB)
#define THREADS 256
#define INNER 4         // rotating prefetch buffers
#define OUTER 5         // SEG / (THREADS*4*INNER)
#define REC 8           // floats per (b,k,seg) record; 6 used
#define NBLK (BB * KK * NSEG)   // 1600

typedef float v4f __attribute__((ext_vector_type(4)));

__global__ void hung_pass1(const float* __restrict__ slot,   // (B,K,N)
                           const float* __restrict__ tgt,    // (B,1,N)
                           float* __restrict__ ws)           // (NBLK, REC)
{
    const int bid = blockIdx.x;            // (b*KK + k)*NSEG + q
    const int q   = bid % NSEG;
    const int bk  = bid / NSEG;            // b*KK + k
    const int b   = bk / KK;

    const float* xk = slot + (size_t)bk * NPIX + q * SEG;
    const float* t  = tgt  + (size_t)b  * NPIX + q * SEG;
    const int tid4  = threadIdx.x * 4;

    float X = 0.f, XF = 0.f, S = 0.f, SF = 0.f, PX = 0.f, Tf = 0.f;

    v4f fgB[INNER], xB[INNER];
    #pragma unroll
    for (int j = 0; j < INNER; ++j) {
        const int off = (j * THREADS) * 4 + tid4;
        fgB[j] = *reinterpret_cast<const v4f*>(t + off);
        xB[j]  = __builtin_nontemporal_load(reinterpret_cast<const v4f*>(xk + off));
    }

    for (int o = 0; o < OUTER; ++o) {
        const int onext = (o + 1 < OUTER) ? o + 1 : 0;   // wrap: harmless reload
        const int nbase = onext * (INNER * THREADS * 4) + tid4;
        #pragma unroll
        for (int j = 0; j < INNER; ++j) {
            const v4f fg4 = fgB[j];
            const v4f x4  = xB[j];
            const int noff = nbase + j * (THREADS * 4);
            fgB[j] = *reinterpret_cast<const v4f*>(t + noff);
            xB[j]  = __builtin_nontemporal_load(reinterpret_cast<const v4f*>(xk + noff));
            #pragma unroll
            for (int u = 0; u < 4; ++u) {
                const float x  = x4[u];
                const float fg = fg4[u];
                const float e  = __expf(-fabsf(x));      // exp(-|x|)
                const float qq = 1.0f + e;
                const float r  = __builtin_amdgcn_rcpf(qq);
                const float d  = __logf(qq) + fmaxf(-x, 0.0f);   // softplus(x)-x
                const float s  = (x >= 0.0f) ? r : e * r;        // sigmoid(x)
                PX += d;
                X  += x;
                XF  = fmaf(x, fg, XF);
                S  += s;
                SF  = fmaf(s, fg, SF);
                Tf += fg;
            }
        }
    }

    // block reduce 6 values: per-wave butterfly (wave=64) then LDS combine
    float v[6] = {X, XF, S, SF, PX, Tf};
    #pragma unroll
    for (int j = 0; j < 6; ++j) {
        float x = v[j];
        #pragma unroll
        for (int off = 32; off > 0; off >>= 1) x += __shfl_down(x, off, 64);
        v[j] = x;
    }
    __shared__ float red[THREADS / 64][6];
    const int lane = threadIdx.x & 63;
    const int w    = threadIdx.x >> 6;
    if (lane == 0) {
        #pragma unroll
        for (int j = 0; j < 6; ++j) red[w][j] = v[j];
    }
    __syncthreads();
    if (threadIdx.x < 6) {
        const int j = threadIdx.x;
        ws[(size_t)bid * REC + j] =
            red[0][j] + red[1][j] + red[2][j] + red[3][j];
    }
}

__global__ __launch_bounds__(320) void hung_pass2(const float* __restrict__ ws,
                                                  float* __restrict__ out)
{
    __shared__ float red[BB][KK][6];
    const int t = threadIdx.x;
    if (t < BB * KK) {                 // t == b*KK + k
        float v[6] = {0, 0, 0, 0, 0, 0};
        #pragma unroll
        for (int q = 0; q < NSEG; ++q) {
            const float* p = ws + (size_t)(t * NSEG + q) * REC;
            #pragma unroll
            for (int j = 0; j < 6; ++j) v[j] += p[j];
        }
        const int b = t / KK, k = t - b * KK;
        #pragma unroll
        for (int j = 0; j < 6; ++j) red[b][k][j] = v[j];
    }
    __syncthreads();
    if (t < BB) {                      // wave 0: one image per lane
        const int b = t;
        const float Tf = red[b][0][5];
        const float Tb = (float)NPIX - Tf;
        float best = 3.402823466e+38f; int kb = 0;
        float xfsum = 0.f, px = 0.f;
        #pragma unroll
        for (int k = 0; k < KK; ++k) {
            const float Sv = red[b][k][2], Iv = red[b][k][3];  // S_k, inter_fg
            const float cf = 1.f - Iv / (Sv + Tf - Iv + 1e-6f);
            const float Ib = Sv - Iv;
            const float cb = 1.f - Ib / (Sv + Tb - Ib + 1e-6f);
            const float dd = cf - cb;
            if (dd < best) { best = dd; kb = k; }  // strict < : ties -> smallest k
            xfsum += red[b][k][1];
            px    += red[b][k][4];
        }
        float res = px + xfsum - (2.f * red[b][kb][1] - red[b][kb][0]);  // - C_{k*}
        #pragma unroll
        for (int off = 32; off > 0; off >>= 1) res += __shfl_down(res, off, 64);
        if (b == 0) out[0] = res * (1.0f / 32768000.0f);   // / (B*K*N)
    }
}

extern "C" void kernel_launch(void* const* d_in, const int* in_sizes, int n_in,
                              void* d_out, int out_size, void* d_ws, size_t ws_size,
                              hipStream_t stream) {
    // setup_inputs order: fg_logits (unused by reference!), slot_logits, target
    const float* slot = (const float*)d_in[1];
    const float* tgt  = (const float*)d_in[2];
    float* out = (float*)d_out;
    float* ws  = (float*)d_ws;

    hung_pass1<<<NBLK, THREADS, 0, stream>>>(slot, tgt, ws);
    hung_pass2<<<1, 320, 0, stream>>>(ws, out);
}

// Round 6
// 223.106 us; speedup vs baseline: 1.0004x; 1.0004x over previous
//
#include <hip/hip_runtime.h>

// HungarianCELoss — analytic collapse of the 120-perm matching.
// targets has only 2 distinct rows (fg, bg=1-fg) => argmin over perms ==
// argmin_k (cost_fg[k]-cost_bg[k]), ties -> smallest k (lex order of perms).
// Per-element identities (x = slot logit, fg = target):
//   e = exp(-|x|); d = softplus(x)-x = log(1+e) + max(-x,0)
//   sigmoid(x) = (x>=0) ? 1/(1+e) : e/(1+e)
//   sum_k A_k = sum d (all k,n) + sum_k XF_k,  C_k = 2*XF_k - X_k
//   answer = [sum_k A_k - C_{k*}] summed over b, / (B*K*N)
//
// R6: pass1 delivered BW is pinned at ~2.2-2.5 TB/s regardless of occupancy
// (R1 vs R4) and in-flight depth (R4 vs R5) -> suspect per-XCD miss-path /
// L2-fill locality. Blocks dispatch round-robin over 8 XCDs by blockIdx, so
// swizzle ids: XCD j gets vid in [j*320,(j+1)*320) == one contiguous 1/8 of
// the address space. Plain (cacheable) loads so L3-warm lines count.

#define BB 64
#define KK 5
#define NPIX 102400     // 320*320
#define QUARTERS 4
#define SEG 25600       // NPIX / QUARTERS (100 KB)
#define ITERS 25        // SEG / (256 threads * 4 floats)
#define THREADS 256
#define REC 8           // floats per (b,k,q) record; 6 used
#define NBLK (BB * KK * QUARTERS)   // 2560 = 10 per CU

typedef float v4f __attribute__((ext_vector_type(4)));

__global__ void hung_pass1(const float* __restrict__ slot,   // (B,K,N)
                           const float* __restrict__ tgt,    // (B,1,N)
                           float* __restrict__ ws)           // (NBLK, REC)
{
    // XCD-contiguity swizzle: bid%8 == XCD id (round-robin dispatch);
    // give XCD j the j-th contiguous 320-segment span of (b,k,q) space.
    const int bid = blockIdx.x;
    const int vid = (bid & 7) * (NBLK / 8) + (bid >> 3);
    const int q   = vid & (QUARTERS - 1);
    const int bk  = vid >> 2;              // b*KK + k (bk-major == contiguous)
    const int b   = bk / KK;

    const float* xk = slot + (size_t)bk * NPIX + q * SEG;
    const float* t  = tgt  + (size_t)b  * NPIX + q * SEG;

    float X = 0.f, XF = 0.f, S = 0.f, SF = 0.f, PX = 0.f, Tf = 0.f;

    const int base = threadIdx.x * 4;
    #pragma unroll 5
    for (int i = 0; i < ITERS; ++i) {
        const int off = base + i * (THREADS * 4);
        const v4f fg4 = *reinterpret_cast<const v4f*>(t  + off);
        const v4f x4  = *reinterpret_cast<const v4f*>(xk + off);
        #pragma unroll
        for (int u = 0; u < 4; ++u) {
            const float x  = x4[u];
            const float fg = fg4[u];
            const float e  = __expf(-fabsf(x));      // exp(-|x|)
            const float qq = 1.0f + e;
            const float r  = __builtin_amdgcn_rcpf(qq);
            const float d  = __logf(qq) + fmaxf(-x, 0.0f);   // softplus(x)-x
            const float s  = (x >= 0.0f) ? r : e * r;        // sigmoid(x)
            PX += d;
            X  += x;
            XF  = fmaf(x, fg, XF);
            S  += s;
            SF  = fmaf(s, fg, SF);
            Tf += fg;
        }
    }

    // block reduce 6 values: per-wave butterfly (wave=64) then LDS combine
    float v[6] = {X, XF, S, SF, PX, Tf};
    #pragma unroll
    for (int j = 0; j < 6; ++j) {
        float x = v[j];
        #pragma unroll
        for (int off = 32; off > 0; off >>= 1) x += __shfl_down(x, off, 64);
        v[j] = x;
    }
    __shared__ float red[THREADS / 64][6];
    const int lane = threadIdx.x & 63;
    const int w    = threadIdx.x >> 6;
    if (lane == 0) {
        #pragma unroll
        for (int j = 0; j < 6; ++j) red[w][j] = v[j];
    }
    __syncthreads();
    if (threadIdx.x < 6) {
        const int j = threadIdx.x;
        ws[(size_t)vid * REC + j] =
            red[0][j] + red[1][j] + red[2][j] + red[3][j];
    }
}

__global__ __launch_bounds__(320) void hung_pass2(const float* __restrict__ ws,
                                                  float* __restrict__ out)
{
    __shared__ float red[BB][KK][6];
    const int t = threadIdx.x;
    if (t < BB * KK) {                 // t == b*KK + k
        float v[6] = {0, 0, 0, 0, 0, 0};
        #pragma unroll
        for (int q = 0; q < QUARTERS; ++q) {
            const float* p = ws + (size_t)(t * QUARTERS + q) * REC;
            #pragma unroll
            for (int j = 0; j < 6; ++j) v[j] += p[j];
        }
        const int b = t / KK, k = t - b * KK;
        #pragma unroll
        for (int j = 0; j < 6; ++j) red[b][k][j] = v[j];
    }
    __syncthreads();
    if (t < BB) {                      // wave 0: one image per lane
        const int b = t;
        const float Tf = red[b][0][5];
        const float Tb = (float)NPIX - Tf;
        float best = 3.402823466e+38f; int kb = 0;
        float xfsum = 0.f, px = 0.f;
        #pragma unroll
        for (int k = 0; k < KK; ++k) {
            const float Sv = red[b][k][2], Iv = red[b][k][3];  // S_k, inter_fg
            const float cf = 1.f - Iv / (Sv + Tf - Iv + 1e-6f);
            const float Ib = Sv - Iv;
            const float cb = 1.f - Ib / (Sv + Tb - Ib + 1e-6f);
            const float dd = cf - cb;
            if (dd < best) { best = dd; kb = k; }  // strict < : ties -> smallest k
            xfsum += red[b][k][1];
            px    += red[b][k][4];
        }
        float res = px + xfsum - (2.f * red[b][kb][1] - red[b][kb][0]);  // - C_{k*}
        #pragma unroll
        for (int off = 32; off > 0; off >>= 1) res += __shfl_down(res, off, 64);
        if (b == 0) out[0] = res * (1.0f / 32768000.0f);   // / (B*K*N)
    }
}

extern "C" void kernel_launch(void* const* d_in, const int* in_sizes, int n_in,
                              void* d_out, int out_size, void* d_ws, size_t ws_size,
                              hipStream_t stream) {
    // setup_inputs order: fg_logits (unused by reference!), slot_logits, target
    const float* slot = (const float*)d_in[1];
    const float* tgt  = (const float*)d_in[2];
    float* out = (float*)d_out;
    float* ws  = (float*)d_ws;

    hung_pass1<<<NBLK, THREADS, 0, stream>>>(slot, tgt, ws);
    hung_pass2<<<1, 320, 0, stream>>>(ws, out);
}